// Round 2
// baseline (63.087 us; speedup 1.0000x reference)
//
#include <hip/hip_runtime.h>

// B=32, C=1, H=W=112, O=64, KH=KW=5, stride=1 -> oh=ow=108
constexpr int KH = 5, KW = 5;
constexpr int O  = 64;
constexpr int D  = KH * KW;          // 25
constexpr int H  = 112, W = 112;
constexpr int OH = H - KH + 1;       // 108
constexpr int OW = W - KW + 1;       // 108
constexpr int P  = OH * OW;          // 11664

// d_ws layout (floats): wTg[25][64] | wTr[25][64] | n2g[64] | n2r[64]
constexpr int WS_FLOATS = 2 * D * O + 2 * O;   // 3328 floats = 13,312 B

__global__ void prep_weights(const float* __restrict__ gw,
                             const float* __restrict__ rw,
                             float* __restrict__ ws) {
    const int o = threadIdx.x;
    if (o >= O) return;
    float sg = 0.f, sr = 0.f;
    #pragma unroll
    for (int k = 0; k < D; ++k) {
        float a = gw[o * D + k]; ws[k * O + o]       = a; sg = fmaf(a, a, sg);
        float b = rw[o * D + k]; ws[(D + k) * O + o] = b; sr = fmaf(b, b, sr);
    }
    ws[2 * D * O + o]     = sg;
    ws[2 * D * O + O + o] = sr;
}

__global__ __launch_bounds__(256, 4) void rbf_main(
    const float* __restrict__ gin, const float* __restrict__ rin,
    const float* __restrict__ ws,  const float* __restrict__ stdp,
    float* __restrict__ out, int B)
{
    const int idx = blockIdx.x * 256 + threadIdx.x;
    if (idx >= B * P) return;
    const int b = idx / P;
    const int p = idx - b * P;
    const int y = p / OW;
    const int x = p - y * OW;

    const float* gb = gin + (b * H + y) * W + x;
    const float* rb = rin + (b * H + y) * W + x;

    // Patch into registers once; accumulate |a|^2.
    float ga[D], ra[D];
    float a2g = 0.f, a2r = 0.f;
    #pragma unroll
    for (int i = 0; i < KH; ++i) {
        #pragma unroll
        for (int j = 0; j < KW; ++j) {
            float g = gb[i * W + j]; ga[i * KW + j] = g; a2g = fmaf(g, g, a2g);
            float r = rb[i * W + j]; ra[i * KW + j] = r; a2r = fmaf(r, r, a2r);
        }
    }

    const float s    = stdp[0];
    const float ninv = -1.0f / (2.0f * s * s);
    const float k2   = ninv * 1.442695040888963f;   // * log2(e)

    const float* wTg = ws;
    const float* wTr = ws + D * O;
    const float* n2g = ws + 2 * D * O;
    const float* n2r = n2g + O;

    float* ob = out + (size_t)b * O * P + p;

    #pragma unroll 1   // keep code size small; 4 iterations of 16 channels
    for (int o0 = 0; o0 < O; o0 += 16) {
        float dg[16], dr[16];
        #pragma unroll
        for (int j = 0; j < 16; ++j) { dg[j] = 0.f; dr[j] = 0.f; }

        #pragma unroll
        for (int k = 0; k < D; ++k) {
            const float g = ga[k];
            const float r = ra[k];
            const float* wg = wTg + k * O + o0;   // wave-uniform -> s_load_dwordx16
            const float* wr = wTr + k * O + o0;
            #pragma unroll
            for (int j = 0; j < 16; ++j) {
                dg[j] = fmaf(g, wg[j], dg[j]);
                dr[j] = fmaf(r, wr[j], dr[j]);
            }
        }

        #pragma unroll
        for (int j = 0; j < 16; ++j) {
            float d2g = fmaxf(fmaf(-2.f, dg[j], a2g + n2g[o0 + j]), 0.f);
            float d2r = fmaxf(fmaf(-2.f, dr[j], a2r + n2r[o0 + j]), 0.f);
            // dist^2 = d2g + d2r + 2*sqrt(d2g*d2r)
            float sq = __builtin_amdgcn_sqrtf(d2g * d2r);
            float t  = fmaf(2.f, sq, d2g + d2r);
            ob[(size_t)(o0 + j) * P] = __builtin_amdgcn_exp2f(k2 * t);
        }
    }
}

// Fallback (round-1 kernel, known-correct) in case ws_size is too small.
__global__ __launch_bounds__(256) void rbf_conv_fallback(
    const float* __restrict__ gin, const float* __restrict__ rin,
    const float* __restrict__ gw,  const float* __restrict__ rw,
    const float* __restrict__ stdp, float* __restrict__ out, int B)
{
    __shared__ float s_w2g[O], s_w2r[O];
    const int t = threadIdx.x;
    if (t < O) {
        float sg = 0.f, sr = 0.f;
        #pragma unroll
        for (int k = 0; k < D; ++k) {
            float a = gw[t * D + k]; sg = fmaf(a, a, sg);
            float b = rw[t * D + k]; sr = fmaf(b, b, sr);
        }
        s_w2g[t] = sg;
        s_w2r[t] = sr;
    }
    __syncthreads();

    const int idx = blockIdx.x * blockDim.x + t;
    if (idx >= B * P) return;
    const int b = idx / P;
    const int p = idx - b * P;
    const int y = p / OW;
    const int x = p - y * OW;

    const float* gb = gin + (b * H + y) * W + x;
    const float* rb = rin + (b * H + y) * W + x;
    float ga[D], ra[D];
    float a2g = 0.f, a2r = 0.f;
    #pragma unroll
    for (int i = 0; i < KH; ++i)
        #pragma unroll
        for (int j = 0; j < KW; ++j) {
            float g = gb[i * W + j]; ga[i * KW + j] = g; a2g = fmaf(g, g, a2g);
            float r = rb[i * W + j]; ra[i * KW + j] = r; a2r = fmaf(r, r, a2r);
        }

    const float s    = stdp[0];
    const float ninv = -1.0f / (2.0f * s * s);
    float* ob = out + (size_t)b * O * P + p;

    for (int o = 0; o < O; ++o) {
        float dg = 0.f, dr = 0.f;
        #pragma unroll
        for (int k = 0; k < D; ++k) {
            dg = fmaf(ga[k], gw[o * D + k], dg);
            dr = fmaf(ra[k], rw[o * D + k], dr);
        }
        float d2g = fmaxf(a2g + s_w2g[o] - 2.0f * dg, 0.f);
        float d2r = fmaxf(a2r + s_w2r[o] - 2.0f * dr, 0.f);
        float dist = __fsqrt_rn(d2g) + __fsqrt_rn(d2r);
        ob[(size_t)o * P] = __expf(ninv * dist * dist);
    }
}

extern "C" void kernel_launch(void* const* d_in, const int* in_sizes, int n_in,
                              void* d_out, int out_size, void* d_ws, size_t ws_size,
                              hipStream_t stream) {
    const float* gin  = (const float*)d_in[0];
    const float* rin  = (const float*)d_in[1];
    const float* gw   = (const float*)d_in[2];
    const float* rw   = (const float*)d_in[3];
    const float* stdp = (const float*)d_in[4];
    float* out = (float*)d_out;

    const int B = in_sizes[0] / (H * W);   // 32
    const int total = B * P;
    const int block = 256;
    const int grid  = (total + block - 1) / block;

    if (ws_size >= WS_FLOATS * sizeof(float) && d_ws != nullptr) {
        float* ws = (float*)d_ws;
        prep_weights<<<1, 64, 0, stream>>>(gw, rw, ws);
        rbf_main<<<grid, block, 0, stream>>>(gin, rin, ws, stdp, out, B);
    } else {
        rbf_conv_fallback<<<grid, block, 0, stream>>>(gin, rin, gw, rw, stdp, out, B);
    }
}